// Round 5
// baseline (105.942 us; speedup 1.0000x reference)
//
#include <hip/hip_runtime.h>

// LearnedTaskSpecificLinear: out[n,o] = sum_i x[n,i] * W[task_ids[n], i, o]
// x: [2048,512] f32, task_ids: [2048] i32, W: [64,512,512] f32, out: [2048,512] f32
//
// Round 9: two live W-staging buffers, always-one-half-ahead (fixes R8's
// per-stage HBM queue drain).
//   grid 512 blocks x 256 thr, 2 blocks/CU (launch_bounds(256,2), VGPR<=256).
//   2 units/block (unit = task x 32-col chunk): u0 = bid, u1 = bid + 512.
//   Decode keeps a task's 16 chunks on one XCD -> x rows L2-resident.
//   Per unit: K in two 256-halves, LDS Wt[2][32x256] f16 (32 KB), k-octet XOR
//   swizzle po = oct ^ (c&7) (verified R5/R7/R8 scheme).
//   NEW: wrE/wrO are BOTH live: {u0h0->E, u0h1->O} issued at kernel top;
//   E is refilled with u1h0 BEFORE the first barrier, O with u1h1 before the
//   second. So at every stageW vmcnt-drain, the other half's 32 KB/block is
//   in flight, and every refill is issued ~2 phases (>1000 cy) before its
//   consume -> HBM queue never drains until the tail. Raw s_barrier +
//   lgkmcnt(0) only (no vmcnt drain at barriers).
//   Register audit (R6 spill lesson): wrE 32 + wrO 32 + pafA/pafB 32 each +
//   xa transient 32 + acc 8 + tval 8 + misc ~25 -> peak ~170 < 256. No spill.

#define NDIM 512
#define KDIM 512
#define NCOL 32
#define KH   256
#define GRID 512

typedef _Float16 f16x8 __attribute__((ext_vector_type(8)));
typedef float    f32x4 __attribute__((ext_vector_type(4)));
typedef int      i32x4 __attribute__((ext_vector_type(4)));

__global__ __launch_bounds__(256, 2) void k_fused5(
    const float* __restrict__ x,
    const int*   __restrict__ tids,
    const float* __restrict__ W,
    float*       __restrict__ out,
    int n_rows)
{
    const int tid  = threadIdx.x;
    const int lane = tid & 63;
    const int wv   = tid >> 6;
    const int ml   = lane & 15;
    const int q    = lane >> 4;
    const int sc4  = (tid & 7) * 4;     // W col group (8 groups x 4 cols)
    const int ob   = tid >> 3;          // W k-octet 0..31 within a half

    __shared__ __align__(16) _Float16 Wt[2][NCOL * KH];   // 2 x 16 KB, swizzled
    __shared__ unsigned short rlw[4 * 128];               // per-wave private lists

    // ---- tids: 8 consecutive rows per lane, vectorized; reused by both units
    const int rbase = wv * 512 + lane * 8;
    int tval[8];
    if (rbase + 7 < n_rows) {
        const i32x4 a = *(const i32x4*)(tids + rbase);
        const i32x4 b = *(const i32x4*)(tids + rbase + 4);
        tval[0] = a[0]; tval[1] = a[1]; tval[2] = a[2]; tval[3] = a[3];
        tval[4] = b[0]; tval[5] = b[1]; tval[6] = b[2]; tval[7] = b[3];
    } else {
        #pragma unroll
        for (int j = 0; j < 8; ++j)
            tval[j] = (rbase + j < n_rows) ? tids[rbase + j] : -1;
    }

    // ---- per-unit mutable state captured by the lambdas
    int   cloc = 0;
    int   c0   = 0;
    const float* xr = x;

    float4 wrE[8], wrO[8];   // two live W staging buffers (named, never indexed)

    auto issueW = [&](const float* Wg, int h, float4 (&wrb)[8]) {
        #pragma unroll
        for (int j = 0; j < 8; ++j)
            wrb[j] = *(const float4*)(Wg + (size_t)(h * KH + ob * 8 + j) * NDIM + sc4);
    };

    auto stageW = [&](int t, const float4 (&wrb)[8]) {   // f32->f16 + swizzled write
        #pragma unroll
        for (int j2 = 0; j2 < 4; ++j2) {
            f16x8 h8;
            #pragma unroll
            for (int j = 0; j < 8; ++j)
                h8[j] = (_Float16)(((const float*)&wrb[j])[j2]);
            const int c  = sc4 + j2;
            const int po = ob ^ (c & 7);
            *(f16x8*)&Wt[t][c * KH + po * 8] = h8;
        }
    };

    auto do_scan = [&](int task) {     // ballot scan -> per-wave private list
        cloc = 0;
        #pragma unroll
        for (int j = 0; j < 8; ++j) {
            const bool m = (tval[j] == task);
            const unsigned long long bal = __ballot(m);
            const int rank = __popcll(bal & ((1ull << lane) - 1ull));
            if (m) rlw[wv * 128 + cloc + rank] = (unsigned short)(rbase + j);
            cloc += __popcll(bal);
        }
    };

    auto load_half = [&](const float* xrp, int t, f16x8* paf) {
        #pragma unroll
        for (int h = 0; h < 2; ++h) {
            f32x4 xa[8];
            #pragma unroll
            for (int k2 = 0; k2 < 4; ++k2) {
                const int ks = h * 4 + k2;
                xa[2 * k2]     = *(const f32x4*)(xrp + t * KH + ks * 32 + q * 8);
                xa[2 * k2 + 1] = *(const f32x4*)(xrp + t * KH + ks * 32 + q * 8 + 4);
            }
            #pragma unroll
            for (int k2 = 0; k2 < 4; ++k2) {
                f16x8 af;
                const float* a0 = (const float*)&xa[2 * k2];
                #pragma unroll
                for (int j = 0; j < 8; ++j) af[j] = (_Float16)a0[j];
                paf[h * 4 + k2] = af;
            }
        }
    };

    auto mma_half = [&](int t, const f16x8* paf, f32x4* acc) {
        #pragma unroll
        for (int ks = 0; ks < 8; ++ks) {
            #pragma unroll
            for (int ct = 0; ct < 2; ++ct) {
                const int cB = ct * 16 + ml;
                const int po = (ks * 4 + q) ^ (cB & 7);
                const f16x8 bf = *(const f16x8*)&Wt[t][cB * KH + po * 8];
                acc[ct] = __builtin_amdgcn_mfma_f32_16x16x32_f16(paf[ks], bf, acc[ct], 0, 0, 0);
            }
        }
    };

    auto store_rows = [&](int g0, const f32x4* acc) {
        #pragma unroll
        for (int rg = 0; rg < 4; ++rg) {
            const int pos = g0 + q * 4 + rg;
            if (pos < cloc) {
                float* op = out + (size_t)rlw[wv * 128 + pos] * NDIM + c0 + ml;
                op[0]  = acc[0][rg];
                op[16] = acc[1][rg];
            }
        }
    };

    auto extras = [&]() {   // rare: wave quarter with >16 matching rows
        for (int g0 = 16; g0 < cloc; g0 += 16) {
            const int idx = g0 + ml;
            const float* xr2 = x + (size_t)rlw[wv * 128 + ((idx < cloc) ? idx : (cloc - 1))] * KDIM;
            f16x8 pf[8];
            f32x4 a2[2] = {};
            load_half(xr2, 0, pf);
            mma_half(0, pf, a2);
            load_half(xr2, 1, pf);
            mma_half(1, pf, a2);
            store_rows(g0, a2);
        }
    };

    // ---- decode both units, issue BOTH halves of unit 0 up front
    const int id0 = blockIdx.x, id1 = blockIdx.x + GRID;
    const int task0 = (id0 & 7) | ((id0 >> 7) << 3);
    const int c00   = ((id0 >> 3) & 15) * NCOL;
    const int task1 = (id1 & 7) | ((id1 >> 7) << 3);
    const int c01   = ((id1 >> 3) & 15) * NCOL;
    const float* Wg0 = W + (size_t)task0 * KDIM * NDIM + c00;
    const float* Wg1 = W + (size_t)task1 * KDIM * NDIM + c01;

    issueW(Wg0, 0, wrE);
    issueW(Wg0, 1, wrO);

    f16x8 pafA[8], pafB[8];
    f32x4 acc[2];

    // ================= unit 0 =================
    do_scan(task0);
    c0 = c00;
    if (cloc > 0) {
        const int idx = (ml < cloc) ? ml : (cloc - 1);
        xr = x + (size_t)rlw[wv * 128 + idx] * KDIM;
        load_half(xr, 0, pafA);
    }

    stageW(0, wrE);              // waits wrE (u0h0); wrO already in flight
    issueW(Wg1, 0, wrE);         // refill E ~2 phases before its consume
    asm volatile("s_waitcnt lgkmcnt(0)" ::: "memory");
    __builtin_amdgcn_s_barrier();
    __builtin_amdgcn_sched_barrier(0);

    acc[0] = (f32x4){}; acc[1] = (f32x4){};
    if (cloc > 0) mma_half(0, pafA, acc);
    if (cloc > 0) load_half(xr, 1, pafB);

    stageW(1, wrO);              // waits wrO (u0h1); wrE (u1h0) in flight
    issueW(Wg1, 1, wrO);         // refill O ~2 phases before its consume
    asm volatile("s_waitcnt lgkmcnt(0)" ::: "memory");
    __builtin_amdgcn_s_barrier();
    __builtin_amdgcn_sched_barrier(0);

    if (cloc > 0) {
        mma_half(1, pafB, acc);
        store_rows(0, acc);
    }
    extras();

    // unit boundary: protect Wt overwrite vs extras readers; u1 loads in flight
    asm volatile("s_waitcnt lgkmcnt(0)" ::: "memory");
    __builtin_amdgcn_s_barrier();
    __builtin_amdgcn_sched_barrier(0);

    // ================= unit 1 =================
    do_scan(task1);
    c0 = c01;
    if (cloc > 0) {
        const int idx = (ml < cloc) ? ml : (cloc - 1);
        xr = x + (size_t)rlw[wv * 128 + idx] * KDIM;
        load_half(xr, 0, pafA);
    }

    stageW(0, wrE);              // waits wrE (u1h0); wrO (u1h1) in flight
    asm volatile("s_waitcnt lgkmcnt(0)" ::: "memory");
    __builtin_amdgcn_s_barrier();
    __builtin_amdgcn_sched_barrier(0);

    acc[0] = (f32x4){}; acc[1] = (f32x4){};
    if (cloc > 0) mma_half(0, pafA, acc);
    if (cloc > 0) load_half(xr, 1, pafB);

    stageW(1, wrO);              // tail: last drain
    asm volatile("s_waitcnt lgkmcnt(0)" ::: "memory");
    __builtin_amdgcn_s_barrier();
    __builtin_amdgcn_sched_barrier(0);

    if (cloc > 0) {
        mma_half(1, pafB, acc);
        store_rows(0, acc);
    }
    extras();
}

extern "C" void kernel_launch(void* const* d_in, const int* in_sizes, int n_in,
                              void* d_out, int out_size, void* d_ws, size_t ws_size,
                              hipStream_t stream) {
    const float* x    = (const float*)d_in[0];
    const int*   tids = (const int*)d_in[1];
    const float* W    = (const float*)d_in[2];
    float*       out  = (float*)d_out;
    const int n_rows  = in_sizes[1];   // 2048

    k_fused5<<<dim3(GRID), dim3(256), 0, stream>>>(x, tids, W, out, n_rows);
}